// Round 4
// baseline (250.462 us; speedup 1.0000x reference)
//
#include <hip/hip_runtime.h>

typedef unsigned short u16;
typedef unsigned int u32;
typedef unsigned long long u64;
typedef __attribute__((ext_vector_type(4))) float f32x4;
typedef __attribute__((ext_vector_type(4))) unsigned short u16x4;
typedef __attribute__((ext_vector_type(4))) short s16x4;
typedef __attribute__((ext_vector_type(8))) short short8;

#define GLOAD16(G, L) __builtin_amdgcn_global_load_lds( \
    (const __attribute__((address_space(1))) void*)(G), \
    (__attribute__((address_space(3))) void*)(L), 16, 0, 0)

__device__ __forceinline__ u16 f2bf(float f) {
  union { float f; unsigned u; } c; c.f = f;
  unsigned u = c.u;
  u += 0x7FFFu + ((u >> 16) & 1u);
  return (u16)(u >> 16);
}

__device__ __forceinline__ void store_out(u16* p, float v) { *p = f2bf(v); }
__device__ __forceinline__ void store_out(float* p, float v) { *p = v; }

// ---------- elementwise f32 -> bf16 ----------
__global__ void k_cvt(const float* __restrict__ in, u16* __restrict__ out, int n4) {
  int i = blockIdx.x * blockDim.x + threadIdx.x;
  if (i >= n4) return;
  const f32x4 v = *(const f32x4*)(in + (size_t)i * 4);
  u16x4 o;
  o[0] = f2bf(v[0]); o[1] = f2bf(v[1]); o[2] = f2bf(v[2]); o[3] = f2bf(v[3]);
  *(u16x4*)(out + (size_t)i * 4) = o;
}

// ---------- transpose+convert+scale: src[R][C] f32 -> dst[C][R] bf16 ----------
__global__ void k_tcvt(const float* __restrict__ src, u16* __restrict__ dst,
                       int R, int C, float scale) {
  __shared__ float t[32][33];
  int bx = blockIdx.x * 32;
  int by = blockIdx.y * 32;
  int tx = threadIdx.x, ty = threadIdx.y;
  #pragma unroll
  for (int j = 0; j < 32; j += 8)
    t[ty + j][tx] = src[(size_t)(by + ty + j) * C + bx + tx];
  __syncthreads();
  #pragma unroll
  for (int j = 0; j < 32; j += 8)
    dst[(size_t)(bx + ty + j) * R + by + tx] = f2bf(t[tx][ty + j] * scale);
}

// ---------- transpose V (bf16): vt[b*1024 + d][t] = kv[b*2048 + t][1024 + d] ----------
__global__ void k_tv(const u16* __restrict__ kv, u16* __restrict__ vt) {
  __shared__ u16 t[32][34];
  int b = blockIdx.z;
  int tb = blockIdx.x * 32;
  int db = blockIdx.y * 32;
  int tx = threadIdx.x, ty = threadIdx.y;
  #pragma unroll
  for (int j = 0; j < 32; j += 8)
    t[ty + j][tx] = kv[(size_t)(b * 2048 + tb + ty + j) * 2048 + 1024 + db + tx];
  __syncthreads();
  #pragma unroll
  for (int j = 0; j < 32; j += 8)
    vt[(size_t)(b * 1024 + db + ty + j) * 2048 + tb + tx] = t[tx][ty + j];
}

// ---------- pack mask into bits: bits[(b*2048+q)*64 + k/32] ----------
__global__ void k_pm(const int* __restrict__ mask, unsigned* __restrict__ bits, int nw) {
  int w = blockIdx.x * blockDim.x + threadIdx.x;
  if (w >= nw) return;
  const int4* p = (const int4*)(mask + (size_t)w * 32);
  unsigned b = 0;
  #pragma unroll
  for (int j = 0; j < 8; ++j) {
    int4 v = p[j];
    b |= (v.x != 0 ? 1u : 0u) << (j * 4);
    b |= (v.y != 0 ? 1u : 0u) << (j * 4 + 1);
    b |= (v.z != 0 ? 1u : 0u) << (j * 4 + 2);
    b |= (v.w != 0 ? 1u : 0u) << (j * 4 + 3);
  }
  bits[w] = b;
}

// ---------- bf16 GEMM: C[M][N] = A[M][K] @ Bt[N][K]^T  (128x128 tile, BK=64) ----------
template <typename OUT_T>
__global__ __launch_bounds__(256) void k_gemm(
    const u16* __restrict__ A, const u16* __restrict__ Bt,
    OUT_T* __restrict__ C, int M, int N, int K)
{
  __shared__ u16 As[128 * 64];
  __shared__ u16 Bs[128 * 64];
  const int tid = threadIdx.x;
  const int lane = tid & 63;
  const int w = tid >> 6;
  const int wr = w >> 1, wc = w & 1;
  const int l16 = lane & 15, lh = lane >> 4;
  const size_t tm = blockIdx.x, tn = blockIdx.y;

  f32x4 acc[4][4] = {};

  for (int kt = 0; kt < K; kt += 64) {
    #pragma unroll
    for (int i = 0; i < 4; ++i) {
      int flat = i * 256 + tid;
      int row = flat >> 3, cb = flat & 7;
      GLOAD16(A + (tm * 128 + row) * K + kt + ((cb ^ (row & 7)) * 8),
              (char*)As + flat * 16);
    }
    #pragma unroll
    for (int i = 0; i < 4; ++i) {
      int flat = i * 256 + tid;
      int row = flat >> 3, cb = flat & 7;
      GLOAD16(Bt + (tn * 128 + row) * K + kt + ((cb ^ (row & 7)) * 8),
              (char*)Bs + flat * 16);
    }
    __syncthreads();
    #pragma unroll
    for (int kk = 0; kk < 2; ++kk) {
      short8 a[4], b[4];
      #pragma unroll
      for (int mi = 0; mi < 4; ++mi) {
        int row = wr * 64 + mi * 16 + l16;
        a[mi] = *(const short8*)&As[row * 64 + ((kk * 32 + lh * 8) ^ ((row & 7) * 8))];
      }
      #pragma unroll
      for (int ni = 0; ni < 4; ++ni) {
        int row = wc * 64 + ni * 16 + l16;
        b[ni] = *(const short8*)&Bs[row * 64 + ((kk * 32 + lh * 8) ^ ((row & 7) * 8))];
      }
      #pragma unroll
      for (int mi = 0; mi < 4; ++mi)
        #pragma unroll
        for (int ni = 0; ni < 4; ++ni)
          acc[mi][ni] = __builtin_amdgcn_mfma_f32_16x16x32_bf16(a[mi], b[ni], acc[mi][ni], 0, 0, 0);
    }
    __syncthreads();
  }
  #pragma unroll
  for (int mi = 0; mi < 4; ++mi)
    #pragma unroll
    for (int ni = 0; ni < 4; ++ni)
      #pragma unroll
      for (int r = 0; r < 4; ++r) {
        size_t row = tm * 128 + wr * 64 + mi * 16 + lh * 4 + r;
        size_t col = tn * 128 + wc * 64 + ni * 16 + l16;
        store_out(&C[row * N + col], acc[mi][ni][r]);
      }
}

// ---------- fused flash attention, S^T formulation ----------
// grid (qt=32, h=16), 512 threads = 8 waves. wave w: batch = w>>2, q-rows = (w&3)*16..+15.
// S^T = mfma(K, Q): C layout gives lane (lh,l16): k = ni*16+lh*4+r (register dim!), q = l16.
//  -> bias loads become f32x4 vectors straight into the C operand
//  -> mask is one u64 per lane per kt
//  -> P stays in registers (cvt_pk pairs along k), PV computed as O^T = mfma(V, P^T)
//     with a matching k-permutation on V's fragment (two ds_read_b64 per tile).
__global__ __launch_bounds__(512, 4) void k_attn(
    const u16* __restrict__ Qp,      // [4096][1024], pre-scaled by 1/8
    const u16* __restrict__ KVp,     // [4096][2048] (cols 0..1023 = K heads)
    const u16* __restrict__ Vt,      // [2048][2048]  Vt[b*1024+h*64+d][t]
    const float* __restrict__ bias,  // [16][2048][2048]
    const unsigned* __restrict__ mbits, // [2][2048][64]
    u16* __restrict__ Ob)            // [4096][1024]
{
  __shared__ u16 Ks[2 * 2 * 64 * 64];  // [buf][batch][k-row][d], 16B-XOR swizzle  32 KB
  __shared__ u16 Vs[2 * 2 * 64 * 64];  // [buf][batch][d-row][t],  8B-XOR swizzle  32 KB
  const int tid = threadIdx.x;
  const int lane = tid & 63;
  const int w = tid >> 6;
  const int bw = w >> 2;           // batch
  const int qs = (w & 3) * 16;     // q offset within 64-row tile
  const int qt = blockIdx.x;
  const int h  = blockIdx.y;
  const int l16 = lane & 15, lh = lane >> 4;
  const int q = qt * 64 + qs + l16;           // this lane's q row (global)

  // staging geometry: per thread one 16B chunk per (batch,tensor); srow 0..63, scb 0..7
  const int srow = tid >> 3, scb = tid & 7;
  // K: 16B-granular XOR swizzle (cb ^ row&7)
  const u16* ksrc = KVp + (size_t)srow * 2048 + h * 64 + ((scb ^ (srow & 7)) * 8);
  // V: 8B-granular XOR swizzle (c8 ^ row&14) — even XOR keeps 16B chunks intact
  const u16* vsrc = Vt + ((size_t)(h * 64 + srow)) * 2048 + (((2 * scb) ^ (srow & 14)) * 4);

  // Q fragments (B-operand of QK^T): row = q = l16, d-slots = kk*32+lh*8+j
  short8 qf[2];
  {
    size_t row = (size_t)bw * 2048 + q;
    qf[0] = *(const short8*)&Qp[row * 1024 + h * 64 + lh * 8];
    qf[1] = *(const short8*)&Qp[row * 1024 + h * 64 + 32 + lh * 8];
  }

  const float* bsrc = bias + ((size_t)h * 2048 + q) * 2048 + lh * 4;   // + kt*64 + ni*16
  const u64*   msrc = (const u64*)(mbits + ((size_t)bw * 2048 + q) * 64); // [kt]

  f32x4 oacc[4] = {};   // O^T: oacc[di][r] = O[q=l16][d = di*16 + lh*4 + r]
  float lpart = 0.f;    // partial row-sum for q (this lane's 16 k's per kt)

  // ---- prologue: stage kt=0 into buf 0; load bias/mask kt=0 ----
  GLOAD16(ksrc + (size_t)(0 * 2048) * 2048, &Ks[0 * 8192 + 0 * 4096 + tid * 8]);
  GLOAD16(ksrc + (size_t)(1 * 2048 + 0) * 2048, &Ks[0 * 8192 + 1 * 4096 + tid * 8]);
  GLOAD16(vsrc + (size_t)(0 * 1024) * 2048, &Vs[0 * 8192 + 0 * 4096 + tid * 8]);
  GLOAD16(vsrc + (size_t)(1 * 1024) * 2048, &Vs[0 * 8192 + 1 * 4096 + tid * 8]);

  f32x4 bias_cur[4];
  #pragma unroll
  for (int ni = 0; ni < 4; ++ni)
    bias_cur[ni] = *(const f32x4*)(bsrc + 0 * 64 + ni * 16);
  u64 mw_cur = msrc[0];

  asm volatile("s_waitcnt vmcnt(0)" ::: "memory");
  __builtin_amdgcn_s_barrier();

  for (int kt = 0; kt < 32; ++kt) {
    const int cur = kt & 1;

    // ---- issue next tile's staging + prefetches (overlap with compute) ----
    f32x4 bias_nxt[4];
    u64 mw_nxt;
    if (kt + 1 < 32) {
      const int nb = cur ^ 1;
      const size_t kro = (size_t)((kt + 1) * 64) * 2048;  // K rows advance
      const size_t vco = (size_t)((kt + 1) * 64);         // V cols advance
      GLOAD16(ksrc + (size_t)(0 * 2048) * 2048 + kro, &Ks[nb * 8192 + 0 * 4096 + tid * 8]);
      GLOAD16(ksrc + (size_t)(1 * 2048) * 2048 + kro, &Ks[nb * 8192 + 1 * 4096 + tid * 8]);
      GLOAD16(vsrc + (size_t)(0 * 1024) * 2048 + vco, &Vs[nb * 8192 + 0 * 4096 + tid * 8]);
      GLOAD16(vsrc + (size_t)(1 * 1024) * 2048 + vco, &Vs[nb * 8192 + 1 * 4096 + tid * 8]);
      #pragma unroll
      for (int ni = 0; ni < 4; ++ni)
        bias_nxt[ni] = *(const f32x4*)(bsrc + (size_t)(kt + 1) * 64 + ni * 16);
      mw_nxt = msrc[kt + 1];
    }

    // ---- S^T = K Q^T + bias : s[ni][r] = S[q=l16][k = ni*16+lh*4+r] ----
    f32x4 s[4];
    #pragma unroll
    for (int ni = 0; ni < 4; ++ni) s[ni] = bias_cur[ni];
    const int kbase = cur * 8192 + bw * 4096;
    #pragma unroll
    for (int kk = 0; kk < 2; ++kk) {
      short8 kf[4];
      #pragma unroll
      for (int ni = 0; ni < 4; ++ni) {
        int row = ni * 16 + l16;
        kf[ni] = *(const short8*)&Ks[kbase + row * 64 + ((kk * 32 + lh * 8) ^ ((row & 7) * 8))];
      }
      #pragma unroll
      for (int ni = 0; ni < 4; ++ni)
        s[ni] = __builtin_amdgcn_mfma_f32_16x16x32_bf16(kf[ni], qf[kk], s[ni], 0, 0, 0);
    }

    // ---- p = mask ? exp(s) : 0 ; per-lane row-sum ; pack to bf16 in regs ----
    u32 pb[4][2];
    {
      unsigned tlo = (unsigned)(mw_cur) >> (lh * 4);
      unsigned thi = (unsigned)(mw_cur >> 32) >> (lh * 4);
      #pragma unroll
      for (int ni = 0; ni < 4; ++ni) {
        unsigned tw = (ni < 2) ? tlo : thi;
        #pragma unroll
        for (int r = 0; r < 4; ++r) {
          unsigned bit = (tw >> ((ni & 1) * 16 + r)) & 1u;
          float pv = bit ? __expf(s[ni][r]) : 0.f;
          lpart += pv;
          s[ni][r] = pv;
        }
        asm("v_cvt_pk_bf16_f32 %0, %1, %2" : "=v"(pb[ni][0]) : "v"(s[ni][0]), "v"(s[ni][1]));
        asm("v_cvt_pk_bf16_f32 %0, %1, %2" : "=v"(pb[ni][1]) : "v"(s[ni][2]), "v"(s[ni][3]));
      }
    }

    // ---- O^T += V * P^T : A = V-frag (two b64 reads, k-permuted to match P) ----
    const int vbase = cur * 8192 + bw * 4096;
    #pragma unroll
    for (int kk = 0; kk < 2; ++kk) {
      union { u32 w[4]; short8 v; } pf;
      pf.w[0] = pb[2 * kk][0];     // slots 0-3:  k = 32kk + lh*4 + j
      pf.w[1] = pb[2 * kk][1];
      pf.w[2] = pb[2 * kk + 1][0]; // slots 4-7:  k = 32kk + 16 + lh*4 + (j-4)
      pf.w[3] = pb[2 * kk + 1][1];
      #pragma unroll
      for (int di = 0; di < 4; ++di) {
        int row = di * 16 + l16;
        int sw = row & 14;
        s16x4 v0 = *(const s16x4*)&Vs[vbase + row * 64 + (((8 * kk + lh) ^ sw) * 4)];
        s16x4 v1 = *(const s16x4*)&Vs[vbase + row * 64 + (((8 * kk + 4 + lh) ^ sw) * 4)];
        short8 vf = __builtin_shufflevector(v0, v1, 0, 1, 2, 3, 4, 5, 6, 7);
        oacc[di] = __builtin_amdgcn_mfma_f32_16x16x32_bf16(vf, pf.v, oacc[di], 0, 0, 0);
      }
    }

    #pragma unroll
    for (int ni = 0; ni < 4; ++ni) bias_cur[ni] = bias_nxt[ni];
    mw_cur = mw_nxt;

    // one drain+barrier per kt: next buffer staged, this buffer's reads done
    asm volatile("s_waitcnt vmcnt(0)" ::: "memory");
    __builtin_amdgcn_s_barrier();
  }

  // ---- epilogue: reduce row-sum across lh groups, divide, pack, store ----
  lpart += __shfl_xor(lpart, 16);
  lpart += __shfl_xor(lpart, 32);
  float inv = 1.0f / lpart;
  size_t orow = (size_t)bw * 2048 + q;
  #pragma unroll
  for (int di = 0; di < 4; ++di)
    #pragma unroll
    for (int rp = 0; rp < 2; ++rp) {
      float v0 = oacc[di][2 * rp] * inv;
      float v1 = oacc[di][2 * rp + 1] * inv;
      u32 pk;
      asm("v_cvt_pk_bf16_f32 %0, %1, %2" : "=v"(pk) : "v"(v0), "v"(v1));
      *(u32*)&Ob[orow * 1024 + h * 64 + di * 16 + lh * 4 + rp * 2] = pk;
    }
}

extern "C" void kernel_launch(void* const* d_in, const int* in_sizes, int n_in,
                              void* d_out, int out_size, void* d_ws, size_t ws_size,
                              hipStream_t stream) {
  const float* query     = (const float*)d_in[0];
  const float* key_value = (const float*)d_in[1];
  const int*   mask      = (const int*)d_in[2];
  const float* bias      = (const float*)d_in[3];
  const float* Wq        = (const float*)d_in[4];
  const float* Wkv       = (const float*)d_in[5];
  const float* Wo        = (const float*)d_in[6];
  float* out = (float*)d_out;

  char* ws = (char*)d_ws;
  u16* qb   = (u16*)(ws);                    // 8 MiB  bf16 query
  u16* kvb  = (u16*)(ws + 8388608);          // 8 MiB  bf16 key_value
  u16* WqT  = (u16*)(ws + 16777216);         // 2 MiB  Wq^T * 0.125
  u16* WkvT = (u16*)(ws + 18874368);         // 4 MiB  Wkv^T
  u16* WoT  = (u16*)(ws + 23068672);         // 2 MiB  Wo^T
  u16* Qp   = (u16*)(ws + 25165824);         // 8 MiB  projected q
  u16* KVp  = (u16*)(ws + 33554432);         // 16 MiB projected kv
  u16* Vt   = (u16*)(ws + 50331648);         // 8 MiB  V transposed
  u16* Ob   = (u16*)(ws + 58720256);         // 8 MiB  attention out
  unsigned* mb = (unsigned*)(ws + 67108864); // 1 MiB  packed mask

  dim3 tb(32, 8);
  k_cvt<<<4096, 256, 0, stream>>>(query, qb, 1048576);
  k_cvt<<<4096, 256, 0, stream>>>(key_value, kvb, 1048576);
  k_tcvt<<<dim3(32, 32), tb, 0, stream>>>(Wq,  WqT,  1024, 1024, 0.125f);
  k_tcvt<<<dim3(64, 32), tb, 0, stream>>>(Wkv, WkvT, 1024, 2048, 1.0f);
  k_tcvt<<<dim3(32, 32), tb, 0, stream>>>(Wo,  WoT,  1024, 1024, 1.0f);
  k_pm<<<1024, 256, 0, stream>>>(mask, mb, 262144);
  k_gemm<u16><<<dim3(32, 8),  256, 0, stream>>>(qb,  WqT,  Qp,  4096, 1024, 1024);
  k_gemm<u16><<<dim3(32, 16), 256, 0, stream>>>(kvb, WkvT, KVp, 4096, 2048, 1024);
  k_tv<<<dim3(64, 32, 2), tb, 0, stream>>>(KVp, Vt);
  k_attn<<<dim3(32, 16), 512, 0, stream>>>(Qp, KVp, Vt, bias, mb, Ob);
  k_gemm<float><<<dim3(32, 8), 256, 0, stream>>>(Ob, WoT, out, 4096, 1024, 1024);
}

// Round 5
// 223.077 us; speedup vs baseline: 1.1228x; 1.1228x over previous
//
#include <hip/hip_runtime.h>

typedef unsigned short u16;
typedef unsigned int u32;
typedef unsigned long long u64;
typedef __attribute__((ext_vector_type(4))) float f32x4;
typedef __attribute__((ext_vector_type(4))) unsigned short u16x4;
typedef __attribute__((ext_vector_type(8))) short short8;

#define GLOAD16(G, L) __builtin_amdgcn_global_load_lds( \
    (const __attribute__((address_space(1))) void*)(G), \
    (__attribute__((address_space(3))) void*)(L), 16, 0, 0)

__device__ __forceinline__ u16 f2bf(float f) {
  union { float f; unsigned u; } c; c.f = f;
  unsigned u = c.u;
  u += 0x7FFFu + ((u >> 16) & 1u);
  return (u16)(u >> 16);
}

__device__ __forceinline__ void store_out(u16* p, float v) { *p = f2bf(v); }
__device__ __forceinline__ void store_out(float* p, float v) { *p = v; }

// ---------- elementwise f32 -> bf16 ----------
__global__ void k_cvt(const float* __restrict__ in, u16* __restrict__ out, int n4) {
  int i = blockIdx.x * blockDim.x + threadIdx.x;
  if (i >= n4) return;
  const f32x4 v = *(const f32x4*)(in + (size_t)i * 4);
  u16x4 o;
  o[0] = f2bf(v[0]); o[1] = f2bf(v[1]); o[2] = f2bf(v[2]); o[3] = f2bf(v[3]);
  *(u16x4*)(out + (size_t)i * 4) = o;
}

// ---------- transpose+convert+scale: src[R][C] f32 -> dst[C][R] bf16 ----------
__global__ void k_tcvt(const float* __restrict__ src, u16* __restrict__ dst,
                       int R, int C, float scale) {
  __shared__ float t[32][33];
  int bx = blockIdx.x * 32;
  int by = blockIdx.y * 32;
  int tx = threadIdx.x, ty = threadIdx.y;
  #pragma unroll
  for (int j = 0; j < 32; j += 8)
    t[ty + j][tx] = src[(size_t)(by + ty + j) * C + bx + tx];
  __syncthreads();
  #pragma unroll
  for (int j = 0; j < 32; j += 8)
    dst[(size_t)(bx + ty + j) * R + by + tx] = f2bf(t[tx][ty + j] * scale);
}

// ---------- transpose V with k-permutation ----------
// vt[b*1024 + d][tblk*64 + i(k)] = kv[b*2048 + t][1024 + d],  k = t & 63,
// i(k) = ((k>>2)&3)*16 + (k>>4)*4 + (k&3)  (so PV fragments are 16B-contiguous)
__global__ void k_tv(const u16* __restrict__ kv, u16* __restrict__ vt) {
  __shared__ u16 sh[32][34];
  int b = blockIdx.z;
  int tb = blockIdx.x * 32;
  int db = blockIdx.y * 32;
  int tx = threadIdx.x, ty = threadIdx.y;
  #pragma unroll
  for (int j = 0; j < 32; j += 8)
    sh[ty + j][tx] = kv[(size_t)(b * 2048 + tb + ty + j) * 2048 + 1024 + db + tx];
  __syncthreads();
  int t = tb + tx;
  int k6 = t & 63;
  int colp = (t & ~63) | (((k6 >> 2) & 3) << 4) | ((k6 >> 4) << 2) | (k6 & 3);
  #pragma unroll
  for (int j = 0; j < 32; j += 8)
    vt[(size_t)(b * 1024 + db + ty + j) * 2048 + colp] = sh[tx][ty + j];
}

// ---------- pack mask into bits: bits[(b*2048+q)*64 + k/32] ----------
__global__ void k_pm(const int* __restrict__ mask, unsigned* __restrict__ bits, int nw) {
  int w = blockIdx.x * blockDim.x + threadIdx.x;
  if (w >= nw) return;
  const int4* p = (const int4*)(mask + (size_t)w * 32);
  unsigned b = 0;
  #pragma unroll
  for (int j = 0; j < 8; ++j) {
    int4 v = p[j];
    b |= (v.x != 0 ? 1u : 0u) << (j * 4);
    b |= (v.y != 0 ? 1u : 0u) << (j * 4 + 1);
    b |= (v.z != 0 ? 1u : 0u) << (j * 4 + 2);
    b |= (v.w != 0 ? 1u : 0u) << (j * 4 + 3);
  }
  bits[w] = b;
}

// ---------- bf16 GEMM: C[M][N] = A[M][K] @ Bt[N][K]^T, tile BM x BN, BK=64 ----------
template <int BM, int BN, typename OUT_T>
__global__ __launch_bounds__(256) void k_gemm(
    const u16* __restrict__ A, const u16* __restrict__ Bt,
    OUT_T* __restrict__ C, int M, int N, int K)
{
  constexpr int MI = BM / 32, NI = BN / 32;   // per-wave acc dims (wave tile = BM/2 x BN/2)
  __shared__ u16 As[BM * 64];
  __shared__ u16 Bs[BN * 64];
  const int tid = threadIdx.x;
  const int lane = tid & 63;
  const int w = tid >> 6;
  const int wr = w >> 1, wc = w & 1;
  const int l16 = lane & 15, lh = lane >> 4;
  const size_t tm = blockIdx.x, tn = blockIdx.y;

  f32x4 acc[MI][NI] = {};

  for (int kt = 0; kt < K; kt += 64) {
    #pragma unroll
    for (int i = 0; i < BM / 32; ++i) {
      int flat = i * 256 + tid;
      int row = flat >> 3, cb = flat & 7;
      GLOAD16(A + (tm * BM + row) * K + kt + ((cb ^ (row & 7)) * 8),
              (char*)As + flat * 16);
    }
    #pragma unroll
    for (int i = 0; i < BN / 32; ++i) {
      int flat = i * 256 + tid;
      int row = flat >> 3, cb = flat & 7;
      GLOAD16(Bt + (tn * BN + row) * K + kt + ((cb ^ (row & 7)) * 8),
              (char*)Bs + flat * 16);
    }
    __syncthreads();
    #pragma unroll
    for (int kk = 0; kk < 2; ++kk) {
      short8 a[MI], b[NI];
      #pragma unroll
      for (int mi = 0; mi < MI; ++mi) {
        int row = wr * (BM / 2) + mi * 16 + l16;
        a[mi] = *(const short8*)&As[row * 64 + ((kk * 32 + lh * 8) ^ ((row & 7) * 8))];
      }
      #pragma unroll
      for (int ni = 0; ni < NI; ++ni) {
        int row = wc * (BN / 2) + ni * 16 + l16;
        b[ni] = *(const short8*)&Bs[row * 64 + ((kk * 32 + lh * 8) ^ ((row & 7) * 8))];
      }
      #pragma unroll
      for (int mi = 0; mi < MI; ++mi)
        #pragma unroll
        for (int ni = 0; ni < NI; ++ni)
          acc[mi][ni] = __builtin_amdgcn_mfma_f32_16x16x32_bf16(a[mi], b[ni], acc[mi][ni], 0, 0, 0);
    }
    __syncthreads();
  }
  #pragma unroll
  for (int mi = 0; mi < MI; ++mi)
    #pragma unroll
    for (int ni = 0; ni < NI; ++ni)
      #pragma unroll
      for (int r = 0; r < 4; ++r) {
        size_t row = tm * BM + wr * (BM / 2) + mi * 16 + lh * 4 + r;
        size_t col = tn * BN + wc * (BN / 2) + ni * 16 + l16;
        store_out(&C[row * N + col], acc[mi][ni][r]);
      }
}

// ---------- fused flash attention, S^T formulation, counted-vmcnt pipeline ----------
// grid (qt=32, h=16), 512 threads = 8 waves; wave w: batch = w>>2, q-rows (w&3)*16..+15.
// Per step: issue stage(kt+1) [4 GLOAD] -> sched_barrier -> consume bias regs ->
// issue bias/mask(kt+1) -> QK^T -> exp/mask -> PV (all b128, XOR-swizzled) ->
// lgkmcnt(0) -> vmcnt(5) (stage drained, bias+mask stay in flight) -> s_barrier.
__global__ __launch_bounds__(512, 4) void k_attn(
    const u16* __restrict__ Qp,      // [4096][1024], pre-scaled by 1/8
    const u16* __restrict__ KVp,     // [4096][2048] (cols 0..1023 = K heads)
    const u16* __restrict__ Vt,      // [2048][2048] permuted (see k_tv)
    const float* __restrict__ bias,  // [16][2048][2048]
    const unsigned* __restrict__ mbits, // [2][2048][64]
    u16* __restrict__ Ob)            // [4096][1024]
{
  __shared__ u16 Ks[2 * 2 * 64 * 64];  // [buf][batch][k-row][d]  32 KB, 16B-XOR
  __shared__ u16 Vs[2 * 2 * 64 * 64];  // [buf][batch][d-row][i]  32 KB, 16B-XOR
  const int tid = threadIdx.x;
  const int lane = tid & 63;
  const int w = tid >> 6;
  const int bw = w >> 2;
  const int qs = (w & 3) * 16;
  const int qt = blockIdx.x;
  const int h  = blockIdx.y;
  const int l16 = lane & 15, lh = lane >> 4;
  const int q = qt * 64 + qs + l16;

  const int srow = tid >> 3, scb = tid & 7;
  const u16* ksrc = KVp + (size_t)srow * 2048 + h * 64 + ((scb ^ (srow & 7)) * 8);
  const u16* vsrc = Vt + ((size_t)(h * 64 + srow)) * 2048 + ((scb ^ (srow & 7)) * 8);

  short8 qf[2];
  {
    size_t row = (size_t)bw * 2048 + q;
    qf[0] = *(const short8*)&Qp[row * 1024 + h * 64 + lh * 8];
    qf[1] = *(const short8*)&Qp[row * 1024 + h * 64 + 32 + lh * 8];
  }

  const float* bsrc = bias + ((size_t)h * 2048 + q) * 2048 + lh * 4;
  const u64*   msrc = (const u64*)(mbits + ((size_t)bw * 2048 + q) * 64);

  f32x4 oacc[4] = {};
  f32x4 lpv = {};
  f32x4 biasA[4], biasB[4];
  u64 mwA, mwB;

  // ---- prologue: stage kt=0 -> buf0; bias/mask kt=0 -> set A ----
  GLOAD16(ksrc,                       &Ks[tid * 8]);
  GLOAD16(ksrc + (size_t)2048 * 2048, &Ks[4096 + tid * 8]);
  GLOAD16(vsrc,                       &Vs[tid * 8]);
  GLOAD16(vsrc + (size_t)1024 * 2048, &Vs[4096 + tid * 8]);
  biasA[0] = *(const f32x4*)(bsrc +  0);
  biasA[1] = *(const f32x4*)(bsrc + 16);
  biasA[2] = *(const f32x4*)(bsrc + 32);
  biasA[3] = *(const f32x4*)(bsrc + 48);
  mwA = msrc[0];
  asm volatile("s_waitcnt vmcnt(0)" ::: "memory");
  __builtin_amdgcn_s_barrier();

#define ASTEP(KT, CUR, BC, MC, BN_, MN_) do {                                            \
    const int ktn_ = ((KT) + 1 < 32) ? (KT) + 1 : 31;                                    \
    GLOAD16(ksrc + (size_t)ktn_ * 64 * 2048,                  &Ks[((CUR)^1) * 8192 + tid * 8]);        \
    GLOAD16(ksrc + ((size_t)2048 + (size_t)ktn_ * 64) * 2048, &Ks[((CUR)^1) * 8192 + 4096 + tid * 8]); \
    GLOAD16(vsrc + (size_t)ktn_ * 64,                         &Vs[((CUR)^1) * 8192 + tid * 8]);        \
    GLOAD16(vsrc + (size_t)1024 * 2048 + (size_t)ktn_ * 64,   &Vs[((CUR)^1) * 8192 + 4096 + tid * 8]); \
    __builtin_amdgcn_sched_barrier(0);                                                   \
    f32x4 s_[4];                                                                         \
    s_[0] = BC[0]; s_[1] = BC[1]; s_[2] = BC[2]; s_[3] = BC[3];                          \
    const unsigned tlo_ = (unsigned)(MC) >> (lh * 4);                                    \
    const unsigned thi_ = (unsigned)((MC) >> 32) >> (lh * 4);                            \
    BN_[0] = *(const f32x4*)(bsrc + (size_t)ktn_ * 64 +  0);                             \
    BN_[1] = *(const f32x4*)(bsrc + (size_t)ktn_ * 64 + 16);                             \
    BN_[2] = *(const f32x4*)(bsrc + (size_t)ktn_ * 64 + 32);                             \
    BN_[3] = *(const f32x4*)(bsrc + (size_t)ktn_ * 64 + 48);                             \
    MN_ = msrc[ktn_];                                                                    \
    const int kb_ = (CUR) * 8192 + bw * 4096;                                            \
    _Pragma("unroll")                                                                    \
    for (int kk = 0; kk < 2; ++kk) {                                                     \
      short8 kf_[4];                                                                     \
      _Pragma("unroll")                                                                  \
      for (int ni = 0; ni < 4; ++ni) {                                                   \
        const int row_ = ni * 16 + l16;                                                  \
        kf_[ni] = *(const short8*)&Ks[kb_ + row_ * 64 + ((kk * 32 + lh * 8) ^ ((row_ & 7) * 8))]; \
      }                                                                                  \
      _Pragma("unroll")                                                                  \
      for (int ni = 0; ni < 4; ++ni)                                                     \
        s_[ni] = __builtin_amdgcn_mfma_f32_16x16x32_bf16(kf_[ni], qf[kk], s_[ni], 0, 0, 0); \
    }                                                                                    \
    _Pragma("unroll")                                                                    \
    for (int kk = 0; kk < 2; ++kk) {                                                     \
      union { u32 wd[4]; short8 v; } pf_;                                                \
      _Pragma("unroll")                                                                  \
      for (int half = 0; half < 2; ++half) {                                             \
        const int ni = 2 * kk + half;                                                    \
        const unsigned tw_ = (ni < 2) ? tlo_ : thi_;                                     \
        _Pragma("unroll")                                                                \
        for (int r = 0; r < 4; ++r) {                                                    \
          const unsigned bit_ = (tw_ >> ((ni & 1) * 16 + r)) & 1u;                       \
          float pv_ = bit_ ? __expf(s_[ni][r]) : 0.f;                                    \
          s_[ni][r] = pv_;                                                               \
        }                                                                                \
        lpv += s_[ni];                                                                   \
        asm("v_cvt_pk_bf16_f32 %0, %1, %2" : "=v"(pf_.wd[2*half])   : "v"(s_[ni][0]), "v"(s_[ni][1])); \
        asm("v_cvt_pk_bf16_f32 %0, %1, %2" : "=v"(pf_.wd[2*half+1]) : "v"(s_[ni][2]), "v"(s_[ni][3])); \
      }                                                                                  \
      _Pragma("unroll")                                                                  \
      for (int di = 0; di < 4; ++di) {                                                   \
        const int row_ = di * 16 + l16;                                                  \
        short8 vf_ = *(const short8*)&Vs[kb_ + row_ * 64 + (((lh * 2 + kk) * 8) ^ ((row_ & 7) * 8))]; \
        oacc[di] = __builtin_amdgcn_mfma_f32_16x16x32_bf16(vf_, pf_.v, oacc[di], 0, 0, 0); \
      }                                                                                  \
    }                                                                                    \
    asm volatile("s_waitcnt lgkmcnt(0)" ::: "memory");                                   \
    asm volatile("s_waitcnt vmcnt(5)" ::: "memory");                                     \
    __builtin_amdgcn_s_barrier();                                                        \
  } while (0)

  for (int kt2 = 0; kt2 < 32; kt2 += 2) {
    ASTEP(kt2,     0, biasA, mwA, biasB, mwB);
    ASTEP(kt2 + 1, 1, biasB, mwB, biasA, mwA);
  }
#undef ASTEP

  // ---- epilogue: reduce row-sum across lh groups, divide, pack, store ----
  float lpart = lpv[0] + lpv[1] + lpv[2] + lpv[3];
  lpart += __shfl_xor(lpart, 16);
  lpart += __shfl_xor(lpart, 32);
  float inv = 1.0f / lpart;
  size_t orow = (size_t)bw * 2048 + q;
  #pragma unroll
  for (int di = 0; di < 4; ++di)
    #pragma unroll
    for (int rp = 0; rp < 2; ++rp) {
      float v0 = oacc[di][2 * rp] * inv;
      float v1 = oacc[di][2 * rp + 1] * inv;
      u32 pk;
      asm("v_cvt_pk_bf16_f32 %0, %1, %2" : "=v"(pk) : "v"(v0), "v"(v1));
      *(u32*)&Ob[orow * 1024 + h * 64 + di * 16 + lh * 4 + rp * 2] = pk;
    }
}

extern "C" void kernel_launch(void* const* d_in, const int* in_sizes, int n_in,
                              void* d_out, int out_size, void* d_ws, size_t ws_size,
                              hipStream_t stream) {
  const float* query     = (const float*)d_in[0];
  const float* key_value = (const float*)d_in[1];
  const int*   mask      = (const int*)d_in[2];
  const float* bias      = (const float*)d_in[3];
  const float* Wq        = (const float*)d_in[4];
  const float* Wkv       = (const float*)d_in[5];
  const float* Wo        = (const float*)d_in[6];
  float* out = (float*)d_out;

  char* ws = (char*)d_ws;
  u16* qb   = (u16*)(ws);                    // 8 MiB  bf16 query
  u16* kvb  = (u16*)(ws + 8388608);          // 8 MiB  bf16 key_value
  u16* WqT  = (u16*)(ws + 16777216);         // 2 MiB  Wq^T * 0.125
  u16* WkvT = (u16*)(ws + 18874368);         // 4 MiB  Wkv^T
  u16* WoT  = (u16*)(ws + 23068672);         // 2 MiB  Wo^T
  u16* Qp   = (u16*)(ws + 25165824);         // 8 MiB  projected q
  u16* KVp  = (u16*)(ws + 33554432);         // 16 MiB projected kv
  u16* Vt   = (u16*)(ws + 50331648);         // 8 MiB  V transposed+permuted
  u16* Ob   = (u16*)(ws + 58720256);         // 8 MiB  attention out
  unsigned* mb = (unsigned*)(ws + 67108864); // 1 MiB  packed mask

  dim3 tb(32, 8);
  k_cvt<<<4096, 256, 0, stream>>>(query, qb, 1048576);
  k_cvt<<<4096, 256, 0, stream>>>(key_value, kvb, 1048576);
  k_tcvt<<<dim3(32, 32), tb, 0, stream>>>(Wq,  WqT,  1024, 1024, 0.125f);
  k_tcvt<<<dim3(64, 32), tb, 0, stream>>>(Wkv, WkvT, 1024, 2048, 1.0f);
  k_tcvt<<<dim3(32, 32), tb, 0, stream>>>(Wo,  WoT,  1024, 1024, 1.0f);
  k_pm<<<1024, 256, 0, stream>>>(mask, mb, 262144);
  k_gemm<64, 128, u16><<<dim3(64, 8),  256, 0, stream>>>(qb,  WqT,  Qp,  4096, 1024, 1024);
  k_gemm<64, 128, u16><<<dim3(64, 16), 256, 0, stream>>>(kvb, WkvT, KVp, 4096, 2048, 1024);
  k_tv<<<dim3(64, 32, 2), tb, 0, stream>>>(KVp, Vt);
  k_attn<<<dim3(32, 16), 512, 0, stream>>>(Qp, KVp, Vt, bias, mb, Ob);
  k_gemm<64, 128, float><<<dim3(64, 8), 256, 0, stream>>>(Ob, WoT, out, 4096, 1024, 1024);
}